// Round 3
// baseline (103.651 us; speedup 1.0000x reference)
//
#include <hip/hip_runtime.h>
#include <hip/hip_bf16.h>

#define NB 8192   // batch
#define ND 512    // feature dim
#define NC 512    // num classes
#define MARGIN_F 1.0f
#define BIGF 3.0e38f

typedef __attribute__((ext_vector_type(8))) short bf16x8;
typedef __attribute__((ext_vector_type(4))) float f32x4;

__device__ __forceinline__ unsigned fkey(float f) {
    unsigned u = __float_as_uint(f);
    unsigned mask = (u & 0x80000000u) ? 0xFFFFFFFFu : 0x80000000u;
    return u ^ mask;
}
__device__ __forceinline__ float finv(unsigned k) {
    unsigned mask = (k & 0x80000000u) ? 0x80000000u : 0xFFFFFFFFu;
    return __uint_as_float(k ^ mask);
}
__device__ __forceinline__ unsigned short f2bf(float f) {
    __hip_bfloat16 h = __float2bfloat16(f);
    return __builtin_bit_cast(unsigned short, h);
}

#define GLOAD_LDS16(g, l)                                                    \
    __builtin_amdgcn_global_load_lds(                                        \
        (const __attribute__((address_space(1))) void*)(g),                  \
        (__attribute__((address_space(3))) void*)(l), 16, 0, 0)

// -------------------------------------------------------------------------
// k0: fp32->bf16 convert (inputs + centers), row/center sqnorms, class
//     histogram, anG init, counter/accumulator zeroing (graph-replay safe).
// -------------------------------------------------------------------------
__global__ __launch_bounds__(256) void k0_prep(
    const float* __restrict__ inputs, const int* __restrict__ targets,
    const float* __restrict__ centers,
    unsigned short* __restrict__ inB, unsigned short* __restrict__ cenB,
    float* __restrict__ rsq, float* __restrict__ csq,
    unsigned* __restrict__ counts, unsigned* __restrict__ anG,
    unsigned* __restrict__ ctrl, unsigned long long* __restrict__ acc2)
{
    const int bid = blockIdx.x;
    const int tid = threadIdx.x;

    if (bid == 2176) {   // histogram + control-state block
        __shared__ unsigned hist[NC];
        if (tid < 65) ctrl[tid] = 0u;            // rctr[64] + gctr
        if (tid == 65) { acc2[0] = 0ull; acc2[1] = 0ull; }
        for (int i = tid; i < NC; i += 256) hist[i] = 0u;
        __syncthreads();
        for (int i = tid; i < NB; i += 256) atomicAdd(&hist[targets[i]], 1u);
        __syncthreads();
        for (int i = tid; i < NC; i += 256) counts[i] = hist[i];
        return;
    }

    const int wave = tid >> 6, lane = tid & 63;
    const float* src;
    unsigned short* dst;
    float* sqdst;
    int row;
    bool is_input = (bid < 2048);
    if (is_input) {
        row   = bid * 4 + wave;
        src   = inputs + (size_t)row * ND;
        dst   = inB + (size_t)row * ND;
        sqdst = rsq + row;
        if (tid < 4) anG[bid * 4 + tid] = 0xFFFFFFFFu;   // re-init each replay
    } else {
        row   = (bid - 2048) * 4 + wave;
        src   = centers + (size_t)row * ND;
        dst   = cenB + (size_t)row * ND;
        sqdst = csq + row;
    }

    float4 v1 = ((const float4*)src)[lane];
    float4 v2 = ((const float4*)src)[lane + 64];
    float s = v1.x*v1.x + v1.y*v1.y + v1.z*v1.z + v1.w*v1.w
            + v2.x*v2.x + v2.y*v2.y + v2.z*v2.z + v2.w*v2.w;

    ushort4 o1, o2;
    o1.x = f2bf(v1.x); o1.y = f2bf(v1.y); o1.z = f2bf(v1.z); o1.w = f2bf(v1.w);
    o2.x = f2bf(v2.x); o2.y = f2bf(v2.y); o2.z = f2bf(v2.z); o2.w = f2bf(v2.w);
    ((ushort4*)dst)[lane]      = o1;
    ((ushort4*)dst)[lane + 64] = o2;

    #pragma unroll
    for (int off = 32; off > 0; off >>= 1) s += __shfl_down(s, off);
    if (lane == 0) *sqdst = s;
}

// -------------------------------------------------------------------------
// k2: round-1's exact pipelined GEMM body (BM=128, BN=64, BK=32, 4 waves,
// 2-phase double-buffered LDS, 512 blocks, ~25 KB LDS -> high occupancy),
// now publishing per-row mins via device atomicMin and finishing the loss
// in-kernel: the last ctile-block per rtile reduces its 128 rows; the last
// of 64 finishers writes out. k3 dispatch eliminated.
// -------------------------------------------------------------------------
__global__ __launch_bounds__(256) void k2_mfma(
    const unsigned short* __restrict__ Ain, const unsigned short* __restrict__ cenB,
    const int* __restrict__ targets, const unsigned* __restrict__ counts,
    const float* __restrict__ csq, const float* __restrict__ rsq,
    unsigned* __restrict__ anG, float* __restrict__ apG,
    unsigned* __restrict__ ctrl, unsigned long long* __restrict__ acc2,
    float* __restrict__ out)
{
    __shared__ __align__(16) unsigned short As[2][128 * 32];  // no pad: global_load_lds layout
    __shared__ __align__(16) unsigned short Bs[2][64 * 32];
    __shared__ int      tgtL[128];
    __shared__ float    csqL[64];
    __shared__ unsigned ldsmin[128];
    __shared__ double   fa[4], fp_[4];
    __shared__ int      isfin;

    const int tid  = threadIdx.x;
    const int w    = tid >> 6;
    const int lane = tid & 63;
    const int wm   = w >> 1;      // 0..1 : 64-row half
    const int wn   = w & 1;       // 0..1 : 32-col half
    const int qd   = lane >> 4;   // quad 0..3
    const int ln   = lane & 15;

    const int bid   = blockIdx.x;
    const int rt    = bid & 63;
    const int rbase = rt * 128;
    const int ct    = bid >> 6;           // 0..7
    const int cbase = ct * 64;

    if (tid < 128) { tgtL[tid] = targets[rbase + tid]; ldsmin[tid] = 0xFFFFFFFFu; }
    if (tid < 64) {
        const int c = cbase + tid;
        csqL[tid] = (counts[c] > 0u) ? csq[c] : BIGF;   // empty class never wins min
    }

    // Staging map (wave-uniform LDS base + lane*16B, m97 pattern).
    const int arow0 = w * 32 + (lane >> 2);
    const int brow  = w * 16 + (lane >> 2);
    const int scol  = (lane & 3) * 8;
    const unsigned short* gA0 = Ain  + (size_t)(rbase + arow0)      * ND + scol;
    const unsigned short* gA1 = Ain  + (size_t)(rbase + arow0 + 16) * ND + scol;
    const unsigned short* gB  = cenB + (size_t)(cbase + brow)       * ND + scol;

    f32x4 acc[4][2] = {};   // 4 row-frags x 2 col-frags of 16x16

#define STAGE(buf, kb) do {                                                  \
        GLOAD_LDS16(gA0 + (kb), &As[buf][(w * 32)      * 32]);               \
        GLOAD_LDS16(gA1 + (kb), &As[buf][(w * 32 + 16) * 32]);               \
        GLOAD_LDS16(gB  + (kb), &Bs[buf][(w * 16)      * 32]);               \
    } while (0)

#define COMPUTE(buf) do {                                                    \
        bf16x8 a[4], b[2];                                                   \
        _Pragma("unroll")                                                    \
        for (int i = 0; i < 4; ++i)                                          \
            a[i] = *(const bf16x8*)&As[buf][(wm * 64 + i * 16 + ln) * 32 + qd * 8]; \
        _Pragma("unroll")                                                    \
        for (int j = 0; j < 2; ++j)                                          \
            b[j] = *(const bf16x8*)&Bs[buf][(wn * 32 + j * 16 + ln) * 32 + qd * 8]; \
        _Pragma("unroll")                                                    \
        for (int i = 0; i < 4; ++i)                                          \
            _Pragma("unroll")                                                \
            for (int j = 0; j < 2; ++j)                                      \
                acc[i][j] = __builtin_amdgcn_mfma_f32_16x16x32_bf16(a[i], b[j], acc[i][j], 0, 0, 0); \
    } while (0)

    STAGE(0, 0);
    __syncthreads();            // drains vmcnt(0): tile 0 visible; LDS state ready
    int cur = 0;
    #pragma unroll
    for (int kb = 32; kb < ND; kb += 32) {
        STAGE(cur ^ 1, kb);     // issue next tile's loads (other buffer, no hazard)
        COMPUTE(cur);           // MFMA+ds_read cover the in-flight load latency
        __syncthreads();        // drain: next tile landed; everyone done reading cur
        cur ^= 1;
    }
    COMPUTE(cur);               // last tile, nothing left to stage

    // Epilogue. C/D layout: col = lane&15, row = (lane>>4)*4 + reg.
    #pragma unroll
    for (int i = 0; i < 4; ++i) {
        #pragma unroll
        for (int r = 0; r < 4; ++r) {
            const int rlocal = wm * 64 + i * 16 + qd * 4 + r;
            const int grow   = rbase + rlocal;
            const int tr     = tgtL[rlocal];
            float m = BIGF;
            #pragma unroll
            for (int j = 0; j < 2; ++j) {
                const int clocal = wn * 32 + j * 16 + ln;
                const float val = csqL[clocal] - 2.0f * acc[i][j][r];
                if (cbase + clocal == tr) {
                    apG[grow] = val;                   // exactly one writer per row
                } else {
                    m = fminf(m, val);
                }
            }
            #pragma unroll
            for (int off = 1; off < 16; off <<= 1)     // min over 16 cols in-wave
                m = fminf(m, __shfl_xor(m, off));
            if (ln == 0) atomicMin(&ldsmin[rlocal], fkey(m));
        }
    }
    __syncthreads();
    if (tid < 128)
        atomicMin(&anG[rbase + tid], ldsmin[tid]);     // device-scope, order-independent

    // ---- arrive: last ctile-block of this rtile becomes the finisher -----
    if (tid == 0) {
        __threadfence();                               // release apG stores (block's L2 -> LLC)
        isfin = (atomicAdd(&ctrl[rt], 1u) == 7u) ? 1 : 0;
    }
    __syncthreads();
    if (!isfin) return;

    // ---- finisher: loss/prec for this rtile's 128 rows + global reduce ---
    __threadfence();                                   // acquire
    double a = 0.0, p = 0.0;
    if (tid < 128) {
        const int r = rbase + tid;
        const unsigned ank = atomicMin(&anG[r], 0xFFFFFFFFu);   // atomic read (no-op write)
        const unsigned apu = atomicOr((unsigned*)apG + r, 0u);  // atomic read
        const float mv  = finv(ank);
        const float apv = __uint_as_float(apu);
        const float s   = rsq[r];
        const float an  = sqrtf(fmaxf(s + mv,  1e-12f));
        const float ap  = sqrtf(fmaxf(s + apv, 1e-12f));
        a = (double)fmaxf(0.0f, ap - an + MARGIN_F);
        p = (an > ap) ? 1.0 : 0.0;
    }
    #pragma unroll
    for (int off = 32; off > 0; off >>= 1) {
        a += __shfl_down(a, off);
        p += __shfl_down(p, off);
    }
    if (lane == 0) { fa[w] = a; fp_[w] = p; }
    __syncthreads();
    if (tid == 0) {
        const double A = fa[0] + fa[1] + fa[2] + fa[3];
        const double P = fp_[0] + fp_[1] + fp_[2] + fp_[3];
        // fixed-point: order-independent, deterministic across dispatch orders
        atomicAdd(&acc2[0], (unsigned long long)(A * 4294967296.0 + 0.5));
        atomicAdd(&acc2[1], (unsigned long long)(P + 0.5));
        __threadfence();
        unsigned* gctr = &ctrl[64];
        if (atomicAdd(gctr, 1u) == 63u) {              // last of 64 finishers
            unsigned long long ls = atomicAdd(&acc2[0], 0ull);
            unsigned long long ps = atomicAdd(&acc2[1], 0ull);
            out[0] = (float)((double)ls / (4294967296.0 * (double)NB));
            out[1] = (float)((double)ps / (double)NB);
        }
    }
}

extern "C" void kernel_launch(void* const* d_in, const int* in_sizes, int n_in,
                              void* d_out, int out_size, void* d_ws, size_t ws_size,
                              hipStream_t stream) {
    const float* inputs  = (const float*)d_in[0];
    const int*   targets = (const int*)d_in[1];
    const float* centers = (const float*)d_in[2];
    float* out = (float*)d_out;

    // ws layout (bytes):
    char* wp = (char*)d_ws;
    unsigned short* inB    = (unsigned short*)(wp);             // 8192*512*2 = 8388608
    unsigned short* cenB   = (unsigned short*)(wp + 8388608);   // 512*512*2  = 524288
    float*          rsq    = (float*)(wp + 8912896);            // 8192*4
    float*          csqv   = (float*)(wp + 8945664);            // 512*4
    unsigned*       counts = (unsigned*)(wp + 8947712);         // 512*4
    float*          apG    = (float*)(wp + 8949760);            // 8192*4
    unsigned*       anG    = (unsigned*)(wp + 8982528);         // 8192*4
    unsigned*       ctrl   = (unsigned*)(wp + 9015296);         // 65*4 (+pad)
    unsigned long long* acc2 = (unsigned long long*)(wp + 9015808); // 16 B

    k0_prep<<<2177, 256, 0, stream>>>(inputs, targets, centers,
                                      inB, cenB, rsq, csqv, counts,
                                      anG, ctrl, acc2);
    k2_mfma<<<512, 256, 0, stream>>>(inB, cenB, targets, counts, csqv, rsq,
                                     anG, apG, ctrl, acc2, out);
}

// Round 4
// 92.247 us; speedup vs baseline: 1.1236x; 1.1236x over previous
//
#include <hip/hip_runtime.h>
#include <hip/hip_bf16.h>

#define NB 8192   // batch
#define ND 512    // feature dim
#define NC 512    // num classes
#define MARGIN_F 1.0f
#define BIGF 3.0e38f

typedef __attribute__((ext_vector_type(8))) short bf16x8;
typedef __attribute__((ext_vector_type(4))) float f32x4;

__device__ __forceinline__ unsigned fkey(float f) {
    unsigned u = __float_as_uint(f);
    unsigned mask = (u & 0x80000000u) ? 0xFFFFFFFFu : 0x80000000u;
    return u ^ mask;
}
__device__ __forceinline__ float finv(unsigned k) {
    unsigned mask = (k & 0x80000000u) ? 0x80000000u : 0xFFFFFFFFu;
    return __uint_as_float(k ^ mask);
}
__device__ __forceinline__ unsigned short f2bf(float f) {
    __hip_bfloat16 h = __float2bfloat16(f);
    return __builtin_bit_cast(unsigned short, h);
}

#define GLOAD_LDS16(g, l)                                                    \
    __builtin_amdgcn_global_load_lds(                                        \
        (const __attribute__((address_space(1))) void*)(g),                  \
        (__attribute__((address_space(3))) void*)(l), 16, 0, 0)

// -------------------------------------------------------------------------
// k0: fp32->bf16 convert (inputs + centers), row/center sqnorms, class
//     histogram, anG init, counter/accumulator zeroing (graph-replay safe).
//     All plain stores: made device-visible by the kernel-boundary release
//     (k2's atomics at the coherent point then see them).
// -------------------------------------------------------------------------
__global__ __launch_bounds__(256) void k0_prep(
    const float* __restrict__ inputs, const int* __restrict__ targets,
    const float* __restrict__ centers,
    unsigned short* __restrict__ inB, unsigned short* __restrict__ cenB,
    float* __restrict__ rsq, float* __restrict__ csq,
    unsigned* __restrict__ counts, unsigned* __restrict__ anG,
    unsigned* __restrict__ ctrl, unsigned long long* __restrict__ acc2)
{
    const int bid = blockIdx.x;
    const int tid = threadIdx.x;

    if (bid == 2176) {   // histogram + control-state block
        __shared__ unsigned hist[NC];
        if (tid < 65) ctrl[tid] = 0u;            // rctr[64] + gctr
        if (tid == 65) { acc2[0] = 0ull; acc2[1] = 0ull; }
        for (int i = tid; i < NC; i += 256) hist[i] = 0u;
        __syncthreads();
        for (int i = tid; i < NB; i += 256) atomicAdd(&hist[targets[i]], 1u);
        __syncthreads();
        for (int i = tid; i < NC; i += 256) counts[i] = hist[i];
        return;
    }

    const int wave = tid >> 6, lane = tid & 63;
    const float* src;
    unsigned short* dst;
    float* sqdst;
    int row;
    bool is_input = (bid < 2048);
    if (is_input) {
        row   = bid * 4 + wave;
        src   = inputs + (size_t)row * ND;
        dst   = inB + (size_t)row * ND;
        sqdst = rsq + row;
        if (tid < 4) anG[bid * 4 + tid] = 0xFFFFFFFFu;   // re-init each replay
    } else {
        row   = (bid - 2048) * 4 + wave;
        src   = centers + (size_t)row * ND;
        dst   = cenB + (size_t)row * ND;
        sqdst = csq + row;
    }

    float4 v1 = ((const float4*)src)[lane];
    float4 v2 = ((const float4*)src)[lane + 64];
    float s = v1.x*v1.x + v1.y*v1.y + v1.z*v1.z + v1.w*v1.w
            + v2.x*v2.x + v2.y*v2.y + v2.z*v2.z + v2.w*v2.w;

    ushort4 o1, o2;
    o1.x = f2bf(v1.x); o1.y = f2bf(v1.y); o1.z = f2bf(v1.z); o1.w = f2bf(v1.w);
    o2.x = f2bf(v2.x); o2.y = f2bf(v2.y); o2.z = f2bf(v2.z); o2.w = f2bf(v2.w);
    ((ushort4*)dst)[lane]      = o1;
    ((ushort4*)dst)[lane + 64] = o2;

    #pragma unroll
    for (int off = 32; off > 0; off >>= 1) s += __shfl_down(s, off);
    if (lane == 0) *sqdst = s;
}

// -------------------------------------------------------------------------
// k2: R1's exact pipelined GEMM body (BM=128, BN=64, BK=32, 4 waves,
// 2-phase double-buffered LDS, 512 blocks, ~25 KB LDS -> high occupancy)
// + FENCE-FREE fused finisher. All cross-block data moves via device-scope
// atomics (sc1, executed at the coherent point -> no buffer_wbl2 anywhere).
// Ordering comes from __syncthreads' per-wave vmcnt(0) drain (covers every
// wave's in-flight atomics, unlike a tid0 threadfence) + one explicit
// s_waitcnt vmcnt(0) in the elect paths.
// -------------------------------------------------------------------------
__global__ __launch_bounds__(256) void k2_mfma(
    const unsigned short* __restrict__ Ain, const unsigned short* __restrict__ cenB,
    const int* __restrict__ targets, const unsigned* __restrict__ counts,
    const float* __restrict__ csq, const float* __restrict__ rsq,
    unsigned* __restrict__ anG, float* __restrict__ apG,
    unsigned* __restrict__ ctrl, unsigned long long* __restrict__ acc2,
    float* __restrict__ out)
{
    __shared__ __align__(16) unsigned short As[2][128 * 32];  // no pad: global_load_lds layout
    __shared__ __align__(16) unsigned short Bs[2][64 * 32];
    __shared__ int      tgtL[128];
    __shared__ float    csqL[64];
    __shared__ unsigned ldsmin[128];
    __shared__ double   fa[4], fp_[4];
    __shared__ int      isfin;

    const int tid  = threadIdx.x;
    const int w    = tid >> 6;
    const int lane = tid & 63;
    const int wm   = w >> 1;      // 0..1 : 64-row half
    const int wn   = w & 1;       // 0..1 : 32-col half
    const int qd   = lane >> 4;   // quad 0..3
    const int ln   = lane & 15;

    const int bid   = blockIdx.x;
    const int rt    = bid & 63;
    const int rbase = rt * 128;
    const int ct    = bid >> 6;           // 0..7
    const int cbase = ct * 64;

    if (tid < 128) { tgtL[tid] = targets[rbase + tid]; ldsmin[tid] = 0xFFFFFFFFu; }
    if (tid < 64) {
        const int c = cbase + tid;
        csqL[tid] = (counts[c] > 0u) ? csq[c] : BIGF;   // empty class never wins min
    }

    // Staging map (wave-uniform LDS base + lane*16B, m97 pattern).
    const int arow0 = w * 32 + (lane >> 2);
    const int brow  = w * 16 + (lane >> 2);
    const int scol  = (lane & 3) * 8;
    const unsigned short* gA0 = Ain  + (size_t)(rbase + arow0)      * ND + scol;
    const unsigned short* gA1 = Ain  + (size_t)(rbase + arow0 + 16) * ND + scol;
    const unsigned short* gB  = cenB + (size_t)(cbase + brow)       * ND + scol;

    f32x4 acc[4][2] = {};   // 4 row-frags x 2 col-frags of 16x16

#define STAGE(buf, kb) do {                                                  \
        GLOAD_LDS16(gA0 + (kb), &As[buf][(w * 32)      * 32]);               \
        GLOAD_LDS16(gA1 + (kb), &As[buf][(w * 32 + 16) * 32]);               \
        GLOAD_LDS16(gB  + (kb), &Bs[buf][(w * 16)      * 32]);               \
    } while (0)

#define COMPUTE(buf) do {                                                    \
        bf16x8 a[4], b[2];                                                   \
        _Pragma("unroll")                                                    \
        for (int i = 0; i < 4; ++i)                                          \
            a[i] = *(const bf16x8*)&As[buf][(wm * 64 + i * 16 + ln) * 32 + qd * 8]; \
        _Pragma("unroll")                                                    \
        for (int j = 0; j < 2; ++j)                                          \
            b[j] = *(const bf16x8*)&Bs[buf][(wn * 32 + j * 16 + ln) * 32 + qd * 8]; \
        _Pragma("unroll")                                                    \
        for (int i = 0; i < 4; ++i)                                          \
            _Pragma("unroll")                                                \
            for (int j = 0; j < 2; ++j)                                      \
                acc[i][j] = __builtin_amdgcn_mfma_f32_16x16x32_bf16(a[i], b[j], acc[i][j], 0, 0, 0); \
    } while (0)

    STAGE(0, 0);
    __syncthreads();            // drains vmcnt(0): tile 0 visible; LDS state ready
    int cur = 0;
    #pragma unroll
    for (int kb = 32; kb < ND; kb += 32) {
        STAGE(cur ^ 1, kb);     // issue next tile's loads (other buffer, no hazard)
        COMPUTE(cur);           // MFMA+ds_read cover the in-flight load latency
        __syncthreads();        // drain: next tile landed; everyone done reading cur
        cur ^= 1;
    }
    COMPUTE(cur);               // last tile, nothing left to stage

    // Epilogue. C/D layout: col = lane&15, row = (lane>>4)*4 + reg.
    // apG published via device atomicExch (coherent point, no fence needed).
    #pragma unroll
    for (int i = 0; i < 4; ++i) {
        #pragma unroll
        for (int r = 0; r < 4; ++r) {
            const int rlocal = wm * 64 + i * 16 + qd * 4 + r;
            const int grow   = rbase + rlocal;
            const int tr     = tgtL[rlocal];
            float m = BIGF;
            #pragma unroll
            for (int j = 0; j < 2; ++j) {
                const int clocal = wn * 32 + j * 16 + ln;
                const float val = csqL[clocal] - 2.0f * acc[i][j][r];
                if (cbase + clocal == tr) {
                    atomicExch((unsigned*)apG + grow, __float_as_uint(val));
                } else {
                    m = fminf(m, val);
                }
            }
            #pragma unroll
            for (int off = 1; off < 16; off <<= 1)     // min over 16 cols in-wave
                m = fminf(m, __shfl_xor(m, off));
            if (ln == 0) atomicMin(&ldsmin[rlocal], fkey(m));
        }
    }
    __syncthreads();                               // ldsmin done; apG exch drained (all waves)
    if (tid < 128)
        atomicMin(&anG[rbase + tid], ldsmin[tid]); // device-scope, order-independent
    __syncthreads();                               // per-wave vmcnt(0): ALL anG atomics complete

    // ---- arrive: last ctile-block of this rtile becomes the finisher -----
    if (tid == 0)
        isfin = (atomicAdd(&ctrl[rt], 1u) == 7u) ? 1 : 0;
    __syncthreads();
    if (!isfin) return;

    // ---- finisher: loss/prec for this rtile's 128 rows + global reduce ---
    // All 8 siblings' publishes are at the coherent point (their barrier
    // drained vmcnt before their ctrl add). Atomic RMW reads see them.
    double a = 0.0, p = 0.0;
    if (tid < 128) {
        const int r = rbase + tid;
        const unsigned ank = atomicMin(&anG[r], 0xFFFFFFFFu);   // atomic read (no-op write)
        const unsigned apu = atomicOr((unsigned*)apG + r, 0u);  // atomic read
        const float mv  = finv(ank);
        const float apv = __uint_as_float(apu);
        const float s   = rsq[r];
        const float an  = sqrtf(fmaxf(s + mv,  1e-12f));
        const float ap  = sqrtf(fmaxf(s + apv, 1e-12f));
        a = (double)fmaxf(0.0f, ap - an + MARGIN_F);
        p = (an > ap) ? 1.0 : 0.0;
    }
    #pragma unroll
    for (int off = 32; off > 0; off >>= 1) {
        a += __shfl_down(a, off);
        p += __shfl_down(p, off);
    }
    if (lane == 0) { fa[w] = a; fp_[w] = p; }
    __syncthreads();
    if (tid == 0) {
        const double A = fa[0] + fa[1] + fa[2] + fa[3];
        const double P = fp_[0] + fp_[1] + fp_[2] + fp_[3];
        // fixed-point: order-independent, deterministic across dispatch orders
        atomicAdd(&acc2[0], (unsigned long long)(A * 4294967296.0 + 0.5));
        atomicAdd(&acc2[1], (unsigned long long)(P + 0.5));
        asm volatile("s_waitcnt vmcnt(0)" ::: "memory");   // acc2 adds complete (no wbl2)
        if (atomicAdd(&ctrl[64], 1u) == 63u) {             // last of 64 finishers
            unsigned long long ls = atomicAdd(&acc2[0], 0ull);
            unsigned long long ps = atomicAdd(&acc2[1], 0ull);
            out[0] = (float)((double)ls / (4294967296.0 * (double)NB));
            out[1] = (float)((double)ps / (double)NB);
        }
    }
}

extern "C" void kernel_launch(void* const* d_in, const int* in_sizes, int n_in,
                              void* d_out, int out_size, void* d_ws, size_t ws_size,
                              hipStream_t stream) {
    const float* inputs  = (const float*)d_in[0];
    const int*   targets = (const int*)d_in[1];
    const float* centers = (const float*)d_in[2];
    float* out = (float*)d_out;

    // ws layout (bytes):
    char* wp = (char*)d_ws;
    unsigned short* inB    = (unsigned short*)(wp);             // 8192*512*2 = 8388608
    unsigned short* cenB   = (unsigned short*)(wp + 8388608);   // 512*512*2  = 524288
    float*          rsq    = (float*)(wp + 8912896);            // 8192*4
    float*          csqv   = (float*)(wp + 8945664);            // 512*4
    unsigned*       counts = (unsigned*)(wp + 8947712);         // 512*4
    float*          apG    = (float*)(wp + 8949760);            // 8192*4
    unsigned*       anG    = (unsigned*)(wp + 8982528);         // 8192*4
    unsigned*       ctrl   = (unsigned*)(wp + 9015296);         // 65*4 (+pad)
    unsigned long long* acc2 = (unsigned long long*)(wp + 9015808); // 16 B

    k0_prep<<<2177, 256, 0, stream>>>(inputs, targets, centers,
                                      inB, cenB, rsq, csqv, counts,
                                      anG, ctrl, acc2);
    k2_mfma<<<512, 256, 0, stream>>>(inB, cenB, targets, counts, csqv, rsq,
                                     anG, apG, ctrl, acc2, out);
}